// Round 12
// baseline (87.172 us; speedup 1.0000x reference)
//
#include <hip/hip_runtime.h>
#include <math.h>

#define CB_M 64      // codewords
#define CB_D 16      // vector dim
#define HARD 5.0f
#define LOG2E 1.44269504088896340736f

typedef __attribute__((ext_vector_type(8))) short bf16x8;  // 8 bf16 = 4 VGPRs
typedef __attribute__((ext_vector_type(4))) float f32x4;
typedef __attribute__((ext_vector_type(4))) int   i32x4;

#if __has_builtin(__builtin_amdgcn_exp2f)
#define EXP2F(x) __builtin_amdgcn_exp2f(x)
#else
#define EXP2F(x) exp2f(x)
#endif

#if __has_builtin(__builtin_amdgcn_rcpf)
#define RCPF(x) __builtin_amdgcn_rcpf(x)
#else
#define RCPF(x) (1.0f / (x))
#endif

__device__ __forceinline__ ushort f2bf_rne(float f) {
    unsigned u = __float_as_uint(f);
    u += 0x7fffu + ((u >> 16) & 1u);       // RNE (prep path only)
    return (ushort)(u >> 16);
}
__device__ __forceinline__ float bf2f(ushort h) {
    return __uint_as_float(((unsigned)h) << 16);
}
// pack [bf16(a) : bf16(b)] into one dword (a = high half), TRUNCATING
__device__ __forceinline__ int pk(float a, float b) {
    return (int)__builtin_amdgcn_perm(__float_as_uint(a), __float_as_uint(b), 0x07060302u);
}
// truncate float to bf16 value (exact residual split)
__device__ __forceinline__ float hi_trunc(float a) {
    return __uint_as_float(__float_as_uint(a) & 0xffff0000u);
}

// Persistent fused kernel, single tile/iter, 5 waves/SIMD.
//   S^T = Rperm @ Xsplit  (codeword permutation cw(t,m)=32(t>>1)+8(m>>2)+
//   4(t&1)+(m&3): softmaxed C-layout regs are exactly a P^T B-operand).
//   Z^T = R^T @ P^T: operand-swapped mfma reuses the SAME fragments and
//   lands each lane 4 contiguous dims of one row -> single dwordx4 store,
//   and the row's 1/denom is already lane-resident (no broadcast shuffles).
__global__ __launch_bounds__(256, 5) void stq_main(const float* __restrict__ x,
                                                   const float* __restrict__ ref,
                                                   float* __restrict__ out,
                                                   int ntiles) {
    __shared__ __align__(16) float  cb_bias[CB_M];
    __shared__ __align__(16) ushort cb_rs_hi[CB_M][CB_D];   // (2H*log2e)*r hi
    __shared__ __align__(16) ushort cb_rs_lo[CB_M][CB_D];   // residual
    __shared__ __align__(16) ushort cb_rzT_hi[CB_D][CB_M];  // r^T (RNE bf16)

    const int tid = threadIdx.x;

    // ---- block-local codebook prep (threads 0..63) ----
    if (tid < CB_M) {
        const f32x4* rp = (const f32x4*)(ref + tid * CB_D);
        f32x4 q0 = rp[0], q1 = rp[1], q2 = rp[2], q3 = rp[3];
        float r[CB_D] = {q0.x,q0.y,q0.z,q0.w, q1.x,q1.y,q1.z,q1.w,
                         q2.x,q2.y,q2.z,q2.w, q3.x,q3.y,q3.z,q3.w};
        float r2 = 0.0f;
#pragma unroll
        for (int j = 0; j < CB_D; ++j) r2 += r[j] * r[j];
        cb_bias[tid] = -(HARD * LOG2E) * r2;
        const float s = 2.0f * HARD * LOG2E;
#pragma unroll
        for (int j = 0; j < CB_D; ++j) {
            float v = s * r[j];
            ushort h = f2bf_rne(v);
            cb_rs_hi[tid][j] = h;
            cb_rs_lo[tid][j] = f2bf_rne(v - bf2f(h));
            cb_rzT_hi[j][tid] = f2bf_rne(r[j]);
        }
    }
    __syncthreads();

    const int lane = tid & 63;
    const int wid  = tid >> 6;
    const int i = lane & 15;        // vector-row index / Z^T col
    const int c = lane >> 4;        // k-octet quad / Z^T dim-quad
    const bool hiquad = (c < 2);
    const int  bmask = hiquad ? -1 : 0;   // zero the residual on lo quads

    // ---- resident fragments ----
    bf16x8 A1[4];                   // S-GEMM A: [r_hi | r_lo] across quads
    f32x4  cinit[4];                // bias splats (free via C operand)
#pragma unroll
    for (int t = 0; t < 4; ++t) {
        const int cwa = 32 * (t >> 1) + 8 * (i >> 2) + 4 * (t & 1) + (i & 3);
        const ushort* src = hiquad ? &cb_rs_hi[cwa][0] : &cb_rs_lo[cwa][0];
        A1[t] = *(const bf16x8*)(src + (c & 1) * 8);
#pragma unroll
        for (int r = 0; r < 4; ++r)
            cinit[t][r] = cb_bias[32 * (t >> 1) + 8 * c + 4 * (t & 1) + r];
    }
    // Z^T-GEMM A operand: A[dim=i][cw=8c+j] = r[cw][dim] (same frag as before)
    bf16x8 AzH0 = *(const bf16x8*)&cb_rzT_hi[i][c * 8];
    bf16x8 AzH1 = *(const bf16x8*)&cb_rzT_hi[i][32 + c * 8];

    const int nwaves = gridDim.x * 4;        // 8192
    int tile = blockIdx.x * 4 + wid;

    // ---- prefetch first tile ----
    f32x4 nxa, nxb;
    {
        const float* xp = x + ((size_t)tile * 16 + i) * CB_D + (c & 1) * 8;
        nxa = *(const f32x4*)xp;
        nxb = *(const f32x4*)(xp + 4);
    }

#pragma unroll 1
    for (; tile < ntiles; tile += nwaves) {
        f32x4 xa = nxa, xb = nxb;
        const int nt = tile + nwaves;
        if (nt < ntiles) {
            const float* xp = x + ((size_t)nt * 16 + i) * CB_D + (c & 1) * 8;
            nxa = *(const f32x4*)xp;
            nxb = *(const f32x4*)(xp + 4);
        }

        // ---- B fragments: B1 = x_hi (trunc), B2 = residual (zeroed on c>=2)
        i32x4 b1, b2;
        b1.x = pk(xa.y, xa.x); b1.y = pk(xa.w, xa.z);
        b1.z = pk(xb.y, xb.x); b1.w = pk(xb.w, xb.z);
        b2.x = pk(xa.y - hi_trunc(xa.y), xa.x - hi_trunc(xa.x)) & bmask;
        b2.y = pk(xa.w - hi_trunc(xa.w), xa.z - hi_trunc(xa.z)) & bmask;
        b2.z = pk(xb.y - hi_trunc(xb.y), xb.x - hi_trunc(xb.x)) & bmask;
        b2.w = pk(xb.w - hi_trunc(xb.w), xb.z - hi_trunc(xb.z)) & bmask;
        bf16x8 B1 = __builtin_bit_cast(bf16x8, b1);
        bf16x8 B2 = __builtin_bit_cast(bf16x8, b2);

        // ---- S^T GEMM: acc[t][r] = logit[cw 32(t>>1)+8c+4(t&1)+r][row i]
        f32x4 acc[4];
#pragma unroll
        for (int t = 0; t < 4; ++t) {
            acc[t] = __builtin_amdgcn_mfma_f32_16x16x32_bf16(A1[t], B1, cinit[t], 0, 0, 0);
            acc[t] = __builtin_amdgcn_mfma_f32_16x16x32_bf16(A1[t], B2, acc[t], 0, 0, 0);
        }

        // ---- row max (lanes {i,16+i,32+i,48+i} hold row i's 64 logits)
        float m01 = fmaxf(fmaxf(acc[0][0], acc[0][1]), fmaxf(acc[0][2], acc[0][3]));
        float m23 = fmaxf(fmaxf(acc[1][0], acc[1][1]), fmaxf(acc[1][2], acc[1][3]));
        float m45 = fmaxf(fmaxf(acc[2][0], acc[2][1]), fmaxf(acc[2][2], acc[2][3]));
        float m67 = fmaxf(fmaxf(acc[3][0], acc[3][1]), fmaxf(acc[3][2], acc[3][3]));
        float lmax = fmaxf(fmaxf(m01, m23), fmaxf(m45, m67));
        lmax = fmaxf(lmax, __shfl_xor(lmax, 16, 64));
        lmax = fmaxf(lmax, __shfl_xor(lmax, 32, 64));

        // ---- exp in place + row sum
        float lsum = 0.0f;
#pragma unroll
        for (int t = 0; t < 4; ++t)
#pragma unroll
            for (int r = 0; r < 4; ++r) {
                acc[t][r] = EXP2F(acc[t][r] - lmax);
                lsum += acc[t][r];
            }
        lsum += __shfl_xor(lsum, 16, 64);
        lsum += __shfl_xor(lsum, 32, 64);
        const float inv = RCPF(lsum);   // row i's 1/denom, resident in-lane

        // ---- pack UNNORMALIZED P^T (B-operand layout: B[cw][vecrow=i])
        i32x4 p1, p2;
        p1.x = pk(acc[0][1], acc[0][0]); p1.y = pk(acc[0][3], acc[0][2]);
        p1.z = pk(acc[1][1], acc[1][0]); p1.w = pk(acc[1][3], acc[1][2]);
        p2.x = pk(acc[2][1], acc[2][0]); p2.y = pk(acc[2][3], acc[2][2]);
        p2.z = pk(acc[3][1], acc[3][0]); p2.w = pk(acc[3][3], acc[3][2]);
        bf16x8 P1 = __builtin_bit_cast(bf16x8, p1);
        bf16x8 P2 = __builtin_bit_cast(bf16x8, p2);

        // ---- Z^T GEMM (operand-swapped): lane gets Z[row i][dims 4c..4c+3]
        f32x4 z = {0.0f, 0.0f, 0.0f, 0.0f};
        z = __builtin_amdgcn_mfma_f32_16x16x32_bf16(AzH0, P1, z, 0, 0, 0);
        z = __builtin_amdgcn_mfma_f32_16x16x32_bf16(AzH1, P2, z, 0, 0, 0);

        // ---- normalize with lane-resident inv, single dwordx4 store
        f32x4 zo;
        zo.x = z.x * inv; zo.y = z.y * inv; zo.z = z.z * inv; zo.w = z.w * inv;
        *(f32x4*)(out + ((size_t)(tile * 16 + i)) * CB_D + 4 * c) = zo;
    }
}

extern "C" void kernel_launch(void* const* d_in, const int* in_sizes, int n_in,
                              void* d_out, int out_size, void* d_ws, size_t ws_size,
                              hipStream_t stream) {
    const float* x   = (const float*)d_in[0];   // (64,8,32,32,16) f32
    const float* ref = (const float*)d_in[1];   // (64,16) f32
    float* out = (float*)d_out;

    const int nvec = in_sizes[0] / CB_D;        // 524288
    const int ntiles = nvec / 16;               // 32768

    stq_main<<<2048, 256, 0, stream>>>(x, ref, out, ntiles);
}